// Round 1
// baseline (6909.573 us; speedup 1.0000x reference)
//
#include <hip/hip_runtime.h>

typedef unsigned short ushort_t;
typedef unsigned int uint_t;
typedef unsigned long long ulong_t;

typedef __bf16 bf16x8 __attribute__((ext_vector_type(8)));
typedef float f32x4 __attribute__((ext_vector_type(4)));
typedef unsigned short u16x4 __attribute__((ext_vector_type(4)));

#define DEV __device__ __forceinline__

// ---------- helpers ----------
DEV ushort_t f2bf(float x) {                 // round-to-nearest-even f32 -> bf16 bits
  uint_t u = __float_as_uint(x);
  u += 0x7fffu + ((u >> 16) & 1u);
  return (ushort_t)(u >> 16);
}
DEV float bf2f(ushort_t h) { return __uint_as_float(((uint_t)h) << 16); }

DEV void gload16(ulong_t g, const ushort_t* l) {
  __builtin_amdgcn_global_load_lds(
      (__attribute__((address_space(1))) void*)g,
      (__attribute__((address_space(3))) void*)(ushort_t*)l,
      16, 0, 0);
}

// ---------- zero init (zero page + stats) ----------
__global__ void zero_k(float* __restrict__ p, int n) {
  int i = blockIdx.x * 256 + threadIdx.x;
  if (i < n) p[i] = 0.f;
}

// ---------- x: NCHW f32 -> NHWC bf16 hi/lo ----------
__global__ __launch_bounds__(256) void cvt_x_k(const float* __restrict__ X,
                                               ushort_t* __restrict__ H,
                                               ushort_t* __restrict__ L) {
  __shared__ float T[64][65];
  const int t = threadIdx.x;
  const int p0 = blockIdx.x * 64;  // global pixel base (0..16383)
  const int c0 = blockIdx.y * 64;  // channel base (0..2047)
  const int b = p0 >> 12;
  const int pin0 = p0 & 4095;
#pragma unroll
  for (int it = 0; it < 4; ++it) {
    const int cl = it * 16 + (t >> 4);
    const int pl = (t & 15) * 4;
    const f32x4 v = *(const f32x4*)&X[((size_t)(b * 2048 + c0 + cl)) * 4096 + pin0 + pl];
#pragma unroll
    for (int j = 0; j < 4; ++j) T[cl][pl + j] = v[j];
  }
  __syncthreads();
#pragma unroll
  for (int it = 0; it < 4; ++it) {
    const int pl = it * 16 + (t >> 4);
    const int cl = (t & 15) * 4;
    u16x4 h, l;
#pragma unroll
    for (int j = 0; j < 4; ++j) {
      float v = T[cl + j][pl];
      ushort_t hh = f2bf(v);
      h[j] = hh;
      l[j] = f2bf(v - bf2f(hh));
    }
    const size_t o = ((size_t)(p0 + pl)) * 2048 + c0 + cl;
    *(u16x4*)&H[o] = h;
    *(u16x4*)&L[o] = l;
  }
}

// ---------- 3x3 weights: OIHW f32 -> [tap][O][I] bf16 hi/lo ----------
__global__ __launch_bounds__(256) void cvt_w3_k(const float* __restrict__ W,
                                                ushort_t* __restrict__ H,
                                                ushort_t* __restrict__ L,
                                                int I, int O) {
  const int t = threadIdx.x;
  const int o = blockIdx.y;
  const int i = blockIdx.x * 256 + t;
  const float* src = W + ((size_t)o * I + i) * 9;
  float v[9];
#pragma unroll
  for (int j = 0; j < 9; ++j) v[j] = src[j];
#pragma unroll
  for (int j = 0; j < 9; ++j) {
    ushort_t h = f2bf(v[j]);
    const size_t d = ((size_t)(j * O + o)) * I + i;
    H[d] = h;
    L[d] = f2bf(v[j] - bf2f(h));
  }
}

// ---------- elementwise f32 -> bf16 hi/lo (Wb: already [O][I]) ----------
__global__ __launch_bounds__(256) void cvt_e_k(const float* __restrict__ W,
                                               ushort_t* __restrict__ H,
                                               ushort_t* __restrict__ L) {
  int i = blockIdx.x * 256 + threadIdx.x;
  float v = W[i];
  ushort_t h = f2bf(v);
  H[i] = h;
  L[i] = f2bf(v - bf2f(h));
}

// ---------- per-channel sum / sumsq over NHWC [16384][512] ----------
__global__ __launch_bounds__(256) void stats_k(const float* __restrict__ X,
                                               float* __restrict__ S,
                                               float* __restrict__ Q) {
  const int t = threadIdx.x;
  const int r0 = blockIdx.x * 32;
  const int c = t * 2;
  float s0 = 0, s1 = 0, q0 = 0, q1 = 0;
  for (int r = 0; r < 32; ++r) {
    const float2 v = *(const float2*)&X[((size_t)(r0 + r)) * 512 + c];
    s0 += v.x; s1 += v.y;
    q0 += v.x * v.x; q1 += v.y * v.y;
  }
  atomicAdd(&S[c], s0); atomicAdd(&S[c + 1], s1);
  atomicAdd(&Q[c], q0); atomicAdd(&Q[c + 1], q1);
}

__global__ void bnparams_k(const float* __restrict__ S, const float* __restrict__ Q,
                           const float* __restrict__ g, const float* __restrict__ b,
                           float* __restrict__ sc, float* __restrict__ sh) {
  const int t = threadIdx.x;  // 512
  const float m = S[t] * (1.0f / 16384.0f);
  const float v = Q[t] * (1.0f / 16384.0f) - m * m;
  const float inv = rsqrtf(v + 1e-5f);
  const float s = g[t] * inv;
  sc[t] = s;
  sh[t] = b[t] - m * s;
}

// ---------- BN + ReLU + split to bf16 hi/lo (NHWC -> NHWC) ----------
__global__ __launch_bounds__(256) void bnact_k(const float* __restrict__ X,
                                               const float* __restrict__ sc,
                                               const float* __restrict__ sh,
                                               ushort_t* __restrict__ H,
                                               ushort_t* __restrict__ L) {
  const size_t i0 = ((size_t)blockIdx.x * 256 + threadIdx.x) * 16;
  const int c0 = (int)(i0 & 511);
#pragma unroll
  for (int q = 0; q < 4; ++q) {
    const f32x4 v = *(const f32x4*)&X[i0 + q * 4];
    const f32x4 s = *(const f32x4*)&sc[c0 + q * 4];
    const f32x4 d = *(const f32x4*)&sh[c0 + q * 4];
    u16x4 h, l;
#pragma unroll
    for (int j = 0; j < 4; ++j) {
      float y = fmaf(v[j], s[j], d[j]);
      y = fmaxf(y, 0.f);
      ushort_t hh = f2bf(y);
      h[j] = hh;
      l[j] = f2bf(y - bf2f(hh));
    }
    *(u16x4*)&H[i0 + q * 4] = h;
    *(u16x4*)&L[i0 + q * 4] = l;
  }
}

// ---------- BN + ReLU + NHWC->NCHW fp32 (first output) ----------
__global__ __launch_bounds__(256) void bn_nchw_k(const float* __restrict__ X,
                                                 const float* __restrict__ sc,
                                                 const float* __restrict__ sh,
                                                 float* __restrict__ O) {
  __shared__ float T[64][65];
  const int t = threadIdx.x;
  const int p0 = blockIdx.x * 64;
  const int c0 = blockIdx.y * 64;
  const int b = p0 >> 12, pin0 = p0 & 4095;
#pragma unroll
  for (int it = 0; it < 4; ++it) {
    const int pl = it * 16 + (t >> 4);
    const int cl = (t & 15) * 4;
    const f32x4 v = *(const f32x4*)&X[((size_t)(p0 + pl)) * 512 + c0 + cl];
#pragma unroll
    for (int j = 0; j < 4; ++j) {
      float y = fmaf(v[j], sc[c0 + cl + j], sh[c0 + cl + j]);
      T[pl][cl + j] = fmaxf(y, 0.f);
    }
  }
  __syncthreads();
#pragma unroll
  for (int it = 0; it < 4; ++it) {
    const int cl = it * 16 + (t >> 4);
    const int pl = (t & 15) * 4;
    f32x4 o;
#pragma unroll
    for (int j = 0; j < 4; ++j) o[j] = T[pl + j][cl];
    *(f32x4*)&O[((size_t)(b * 512 + c0 + cl)) * 4096 + pin0 + pl] = o;
  }
}

// ---------- 1x1 classifier: (BN+ReLU)(conv1_raw) x W4 + b4 -> NCHW ----------
__global__ __launch_bounds__(256) void conv4_k(const float* __restrict__ X,
                                               const float* __restrict__ sc,
                                               const float* __restrict__ sh,
                                               const float* __restrict__ W4,
                                               const float* __restrict__ B4,
                                               float* __restrict__ O) {
  __shared__ float A[256][69];
  __shared__ float WL[64][19];
  const int t = threadIdx.x;
  const int g0 = blockIdx.x * 256;
  float acc[19];
#pragma unroll
  for (int n = 0; n < 19; ++n) acc[n] = 0.f;
  for (int kc = 0; kc < 8; ++kc) {
    const int k0 = kc * 64;
    __syncthreads();
#pragma unroll
    for (int it = 0; it < 16; ++it) {
      const int rl = it * 16 + (t >> 4);
      const int cl = (t & 15) * 4;
      const f32x4 v = *(const f32x4*)&X[((size_t)(g0 + rl)) * 512 + k0 + cl];
#pragma unroll
      for (int j = 0; j < 4; ++j)
        A[rl][cl + j] = fmaxf(fmaf(v[j], sc[k0 + cl + j], sh[k0 + cl + j]), 0.f);
    }
    for (int e = t; e < 1216; e += 256) {
      int k = e / 19, n = e - k * 19;
      WL[k][n] = W4[(size_t)n * 512 + k0 + k];
    }
    __syncthreads();
#pragma unroll 8
    for (int k = 0; k < 64; ++k) {
      const float a = A[t][k];
#pragma unroll
      for (int n = 0; n < 19; ++n) acc[n] = fmaf(a, WL[k][n], acc[n]);
    }
  }
  const int g = g0 + t;
  const int b = g >> 12, pin = g & 4095;
#pragma unroll
  for (int n = 0; n < 19; ++n)
    O[((size_t)(b * 19 + n)) * 4096 + pin] = acc[n] + B4[n];
}

// ---------- main implicit-GEMM conv (split-bf16, 3 MFMA products) ----------
// Tile 128x128, BK=32, 256 threads (4 waves, 2x2), wave tile 64x64.
// LDS frag-blocked: slot s holds one 16x32 fragment (1024B), lane l owns 16B at s*1024+l*16.
// Slots: [0..7] A_hi m-frags, [8..15] A_lo, [16..23] B_hi n-frags, [24..31] B_lo.
template <int EPI>  // 0: fp32 NHWC store; 1: +bias then bf16 hi/lo NHWC store
__global__ __launch_bounds__(256, 2) void gemm_k(
    const ushort_t* __restrict__ A1h, const ushort_t* __restrict__ A1l, int C1,
    const ushort_t* __restrict__ A2h, const ushort_t* __restrict__ A2l, int C2,
    const ushort_t* __restrict__ Bh_, const ushort_t* __restrict__ Bl_,
    int taps, int Nc, int KS, const ushort_t* __restrict__ zp,
    float* __restrict__ Co, ushort_t* __restrict__ Ch, ushort_t* __restrict__ Cl,
    const float* __restrict__ bias) {
  __shared__ ushort_t lds[2][16384];  // 2 x 32KB
  const int t = threadIdx.x;
  const int lane = t & 63;
  const int wid = t >> 6;
  const int wr = wid >> 1, wc = wid & 1;
  const int bx = blockIdx.x;  // n tile
  const int by = blockIdx.y;  // m tile (0..127)
  const int Ctot = C1 + C2;
  const int klo = (lane >> 4) * 8;
  const bool isA = wid < 2;
  const int bbase = (by >> 5) * 4096;  // batch pixel base

  int ph[8], pw[8];
  ulong_t g8[8];
  if (isA) {
#pragma unroll
    for (int f = 0; f < 8; ++f) {
      int p = ((by & 31) * 128) + f * 16 + (lane & 15);  // pixel-in-batch
      ph[f] = p >> 6;
      pw[f] = p & 63;
    }
  }
  int tap = 0, c0 = 0;

  auto recompute = [&]() {
    if (isA) {
      const ushort_t* base;
      int C, cc;
      if (c0 < C1) { base = (wid == 0) ? A1h : A1l; C = C1; cc = c0; }
      else         { base = (wid == 0) ? A2h : A2l; C = C2; cc = c0 - C1; }
      const int kh = tap / 3;
      const int dy = (taps == 9) ? (kh - 1) : 0;
      const int dx = (taps == 9) ? (tap - kh * 3 - 1) : 0;
#pragma unroll
      for (int f = 0; f < 8; ++f) {
        const int h2 = ph[f] + dy, w2 = pw[f] + dx;
        const bool ok = ((unsigned)h2 < 64u) & ((unsigned)w2 < 64u);
        const int sp = bbase + (h2 << 6) + w2;
        const ushort_t* p = base + (size_t)sp * (size_t)C + cc + klo;
        g8[f] = ok ? (ulong_t)p : (ulong_t)zp;
      }
    } else {
      const ushort_t* base = (wid == 2) ? Bh_ : Bl_;
#pragma unroll
      for (int f = 0; f < 8; ++f) {
        const int cout = bx * 128 + f * 16 + (lane & 15);
        g8[f] = (ulong_t)(base + ((size_t)(tap * Nc + cout)) * (size_t)Ctot + c0 + klo);
      }
    }
  };

  auto stage = [&](int buf) {
    ushort_t* lb = &lds[buf][wid * 8 * 512];
#pragma unroll
    for (int f = 0; f < 8; ++f) {
      gload16(g8[f], lb + f * 512);
      g8[f] += 64;  // +32 channels (bytes)
    }
  };

  auto advance = [&]() {
    c0 += 32;
    if (c0 == Ctot) {
      c0 = 0;
      ++tap;
      if (tap < taps) recompute();
    } else if (c0 == C1 && C2 > 0 && isA) {
      recompute();  // concat region switch
    }
  };

  f32x4 acc[4][4];
#pragma unroll
  for (int i = 0; i < 4; ++i)
#pragma unroll
    for (int j = 0; j < 4; ++j) acc[i][j] = (f32x4){0.f, 0.f, 0.f, 0.f};

  recompute();
  stage(0);
  advance();

  const int lofs = lane * 8;
  int buf = 0;
  for (int ks = 0; ks < KS; ++ks) {
    asm volatile("s_waitcnt vmcnt(0)" ::: "memory");
    __syncthreads();
    if (ks + 1 < KS) { stage(buf ^ 1); advance(); }
    const ushort_t* L = &lds[buf][0];
    bf16x8 ah[4], al[4], bh[4], bl[4];
#pragma unroll
    for (int i = 0; i < 4; ++i) {
      ah[i] = *(const bf16x8*)(L + (wr * 4 + i) * 512 + lofs);
      al[i] = *(const bf16x8*)(L + (8 + wr * 4 + i) * 512 + lofs);
      bh[i] = *(const bf16x8*)(L + (16 + wc * 4 + i) * 512 + lofs);
      bl[i] = *(const bf16x8*)(L + (24 + wc * 4 + i) * 512 + lofs);
    }
#pragma unroll
    for (int mi = 0; mi < 4; ++mi)
#pragma unroll
      for (int ni = 0; ni < 4; ++ni)
        acc[mi][ni] = __builtin_amdgcn_mfma_f32_16x16x32_bf16(ah[mi], bh[ni], acc[mi][ni], 0, 0, 0);
#pragma unroll
    for (int mi = 0; mi < 4; ++mi)
#pragma unroll
      for (int ni = 0; ni < 4; ++ni) {
        acc[mi][ni] = __builtin_amdgcn_mfma_f32_16x16x32_bf16(ah[mi], bl[ni], acc[mi][ni], 0, 0, 0);
        acc[mi][ni] = __builtin_amdgcn_mfma_f32_16x16x32_bf16(al[mi], bh[ni], acc[mi][ni], 0, 0, 0);
      }
    buf ^= 1;
  }

  // epilogue: C/D layout col=lane&15, row=(lane>>4)*4+j  [m89-verified]
  const int row0 = by * 128 + wr * 64;
  const int col0 = bx * 128 + wc * 64;
  if (EPI == 0) {
#pragma unroll
    for (int mi = 0; mi < 4; ++mi)
#pragma unroll
      for (int ni = 0; ni < 4; ++ni) {
        const int c = col0 + ni * 16 + (lane & 15);
#pragma unroll
        for (int j = 0; j < 4; ++j) {
          const int r = row0 + mi * 16 + (lane >> 4) * 4 + j;
          Co[(size_t)r * Nc + c] = acc[mi][ni][j];
        }
      }
  } else {
#pragma unroll
    for (int ni = 0; ni < 4; ++ni) {
      const int c = col0 + ni * 16 + (lane & 15);
      const float bv = bias[c];
#pragma unroll
      for (int mi = 0; mi < 4; ++mi)
#pragma unroll
        for (int j = 0; j < 4; ++j) {
          const int r = row0 + mi * 16 + (lane >> 4) * 4 + j;
          float v = acc[mi][ni][j] + bv;
          ushort_t h = f2bf(v);
          float lo = v - bf2f(h);
          Ch[(size_t)r * Nc + c] = h;
          Cl[(size_t)r * Nc + c] = f2bf(lo);
        }
    }
  }
}

// ---------- host ----------
extern "C" void kernel_launch(void* const* d_in, const int* in_sizes, int n_in,
                              void* d_out, int out_size, void* d_ws, size_t ws_size,
                              hipStream_t stream) {
  const float* x  = (const float*)d_in[0];
  const float* Wa = (const float*)d_in[1];
  const float* ga = (const float*)d_in[2];
  const float* ba = (const float*)d_in[3];
  const float* Wb = (const float*)d_in[4];
  const float* bb = (const float*)d_in[5];
  const float* W1 = (const float*)d_in[6];
  const float* g1 = (const float*)d_in[7];
  const float* b1 = (const float*)d_in[8];
  const float* W4 = (const float*)d_in[9];
  const float* b4 = (const float*)d_in[10];
  float* out0 = (float*)d_out;
  float* outF = out0 + (size_t)4 * 512 * 64 * 64;

  char* ws = (char*)d_ws;
  size_t off = 0;
  auto take = [&](size_t bytes) -> char* {
    char* p = ws + off;
    off += (bytes + 255) & ~(size_t)255;
    return p;
  };
  ushort_t* zp  = (ushort_t*)take(8192);
  float* sumA = (float*)take(2048);
  float* ssA  = (float*)take(2048);
  float* scA  = (float*)take(2048);
  float* shA  = (float*)take(2048);
  float* sum1 = (float*)take(2048);
  float* ss1  = (float*)take(2048);
  float* sc1  = (float*)take(2048);
  float* sh1  = (float*)take(2048);
  ushort_t* xh  = (ushort_t*)take((size_t)16384 * 2048 * 2);
  ushort_t* xl  = (ushort_t*)take((size_t)16384 * 2048 * 2);
  ushort_t* wah = (ushort_t*)take((size_t)9 * 512 * 2048 * 2);
  ushort_t* wal = (ushort_t*)take((size_t)9 * 512 * 2048 * 2);
  ushort_t* w1h = (ushort_t*)take((size_t)9 * 512 * 2560 * 2);
  ushort_t* w1l = (ushort_t*)take((size_t)9 * 512 * 2560 * 2);
  ushort_t* wbh = (ushort_t*)take((size_t)512 * 512 * 2);
  ushort_t* wbl = (ushort_t*)take((size_t)512 * 512 * 2);
  char* r1 = take((size_t)16384 * 512 * 4);  // conva_raw f32, later outB hi/lo
  char* r2 = take((size_t)16384 * 512 * 4);  // outA hi/lo, later conv1_raw f32
  if (ws_size < off) return;  // workspace too small: bail (diagnosable next round)

  float* convaRaw = (float*)r1;
  ushort_t* oBh = (ushort_t*)r1;
  ushort_t* oBl = (ushort_t*)(r1 + (size_t)16384 * 512 * 2);
  ushort_t* oAh = (ushort_t*)r2;
  ushort_t* oAl = (ushort_t*)(r2 + (size_t)16384 * 512 * 2);
  float* conv1Raw = (float*)r2;

  zero_k<<<dim3(24), dim3(256), 0, stream>>>((float*)ws, 6144);
  cvt_x_k<<<dim3(256, 32), dim3(256), 0, stream>>>(x, xh, xl);
  cvt_w3_k<<<dim3(8, 512), dim3(256), 0, stream>>>(Wa, wah, wal, 2048, 512);
  cvt_w3_k<<<dim3(10, 512), dim3(256), 0, stream>>>(W1, w1h, w1l, 2560, 512);
  cvt_e_k<<<dim3(1024), dim3(256), 0, stream>>>(Wb, wbh, wbl);

  // conva: 3x3, K = 9*2048
  gemm_k<0><<<dim3(4, 128), dim3(256), 0, stream>>>(
      xh, xl, 2048, (const ushort_t*)nullptr, (const ushort_t*)nullptr, 0,
      wah, wal, 9, 512, 576, zp, convaRaw, nullptr, nullptr, nullptr);
  stats_k<<<dim3(512), dim3(256), 0, stream>>>(convaRaw, sumA, ssA);
  bnparams_k<<<dim3(1), dim3(512), 0, stream>>>(sumA, ssA, ga, ba, scA, shA);
  bnact_k<<<dim3(2048), dim3(256), 0, stream>>>(convaRaw, scA, shA, oAh, oAl);

  // convb: 1x1 + bias, K = 512 (outputs split to bf16 hi/lo for concat)
  gemm_k<1><<<dim3(4, 128), dim3(256), 0, stream>>>(
      oAh, oAl, 512, (const ushort_t*)nullptr, (const ushort_t*)nullptr, 0,
      wbh, wbl, 1, 512, 16, zp, nullptr, oBh, oBl, bb);

  // conv1: 3x3 over concat [x(2048) | outB(512)], K = 9*2560
  gemm_k<0><<<dim3(4, 128), dim3(256), 0, stream>>>(
      xh, xl, 2048, oBh, oBl, 512,
      w1h, w1l, 9, 512, 720, zp, conv1Raw, nullptr, nullptr, nullptr);
  stats_k<<<dim3(512), dim3(256), 0, stream>>>(conv1Raw, sum1, ss1);
  bnparams_k<<<dim3(1), dim3(512), 0, stream>>>(sum1, ss1, g1, b1, sc1, sh1);

  bn_nchw_k<<<dim3(256, 8), dim3(256), 0, stream>>>(conv1Raw, sc1, sh1, out0);
  conv4_k<<<dim3(64), dim3(256), 0, stream>>>(conv1Raw, sc1, sh1, W4, b4, outF);
}

// Round 3
// 5661.731 us; speedup vs baseline: 1.2204x; 1.2204x over previous
//
#include <hip/hip_runtime.h>

typedef unsigned short ushort_t;
typedef unsigned int uint_t;
typedef unsigned long long ulong_t;

typedef __bf16 bf16x8 __attribute__((ext_vector_type(8)));
typedef float f32x4 __attribute__((ext_vector_type(4)));
typedef unsigned short u16x4 __attribute__((ext_vector_type(4)));

#define DEV __device__ __forceinline__

// ---------- helpers ----------
DEV ushort_t f2bf(float x) {                 // round-to-nearest-even f32 -> bf16 bits
  uint_t u = __float_as_uint(x);
  u += 0x7fffu + ((u >> 16) & 1u);
  return (ushort_t)(u >> 16);
}
DEV float bf2f(ushort_t h) { return __uint_as_float(((uint_t)h) << 16); }

DEV void gload16(ulong_t g, const ushort_t* l) {
  __builtin_amdgcn_global_load_lds(
      (__attribute__((address_space(1))) void*)g,
      (__attribute__((address_space(3))) void*)(ushort_t*)l,
      16, 0, 0);
}

// ---------- zero init (zero page + stats) ----------
__global__ void zero_k(float* __restrict__ p, int n) {
  int i = blockIdx.x * 256 + threadIdx.x;
  if (i < n) p[i] = 0.f;
}

// ---------- x: NCHW f32 -> NHWC bf16 hi/lo ----------
__global__ __launch_bounds__(256) void cvt_x_k(const float* __restrict__ X,
                                               ushort_t* __restrict__ H,
                                               ushort_t* __restrict__ L) {
  __shared__ float T[64][65];
  const int t = threadIdx.x;
  const int p0 = blockIdx.x * 64;  // global pixel base (0..16383)
  const int c0 = blockIdx.y * 64;  // channel base (0..2047)
  const int b = p0 >> 12;
  const int pin0 = p0 & 4095;
#pragma unroll
  for (int it = 0; it < 4; ++it) {
    const int cl = it * 16 + (t >> 4);
    const int pl = (t & 15) * 4;
    const f32x4 v = *(const f32x4*)&X[((size_t)(b * 2048 + c0 + cl)) * 4096 + pin0 + pl];
#pragma unroll
    for (int j = 0; j < 4; ++j) T[cl][pl + j] = v[j];
  }
  __syncthreads();
#pragma unroll
  for (int it = 0; it < 4; ++it) {
    const int pl = it * 16 + (t >> 4);
    const int cl = (t & 15) * 4;
    u16x4 h, l;
#pragma unroll
    for (int j = 0; j < 4; ++j) {
      float v = T[cl + j][pl];
      ushort_t hh = f2bf(v);
      h[j] = hh;
      l[j] = f2bf(v - bf2f(hh));
    }
    const size_t o = ((size_t)(p0 + pl)) * 2048 + c0 + cl;
    *(u16x4*)&H[o] = h;
    *(u16x4*)&L[o] = l;
  }
}

// ---------- 3x3 weights: OIHW f32 -> [tap][O][I] bf16 hi/lo ----------
__global__ __launch_bounds__(256) void cvt_w3_k(const float* __restrict__ W,
                                                ushort_t* __restrict__ H,
                                                ushort_t* __restrict__ L,
                                                int I, int O) {
  const int t = threadIdx.x;
  const int o = blockIdx.y;
  const int i = blockIdx.x * 256 + t;
  const float* src = W + ((size_t)o * I + i) * 9;
  float v[9];
#pragma unroll
  for (int j = 0; j < 9; ++j) v[j] = src[j];
#pragma unroll
  for (int j = 0; j < 9; ++j) {
    ushort_t h = f2bf(v[j]);
    const size_t d = ((size_t)(j * O + o)) * I + i;
    H[d] = h;
    L[d] = f2bf(v[j] - bf2f(h));
  }
}

// ---------- elementwise f32 -> bf16 hi/lo (Wb: already [O][I]) ----------
__global__ __launch_bounds__(256) void cvt_e_k(const float* __restrict__ W,
                                               ushort_t* __restrict__ H,
                                               ushort_t* __restrict__ L) {
  int i = blockIdx.x * 256 + threadIdx.x;
  float v = W[i];
  ushort_t h = f2bf(v);
  H[i] = h;
  L[i] = f2bf(v - bf2f(h));
}

// ---------- per-channel sum / sumsq over NHWC [16384][512] ----------
__global__ __launch_bounds__(256) void stats_k(const float* __restrict__ X,
                                               float* __restrict__ S,
                                               float* __restrict__ Q) {
  const int t = threadIdx.x;
  const int r0 = blockIdx.x * 32;
  const int c = t * 2;
  float s0 = 0, s1 = 0, q0 = 0, q1 = 0;
  for (int r = 0; r < 32; ++r) {
    const float2 v = *(const float2*)&X[((size_t)(r0 + r)) * 512 + c];
    s0 += v.x; s1 += v.y;
    q0 += v.x * v.x; q1 += v.y * v.y;
  }
  atomicAdd(&S[c], s0); atomicAdd(&S[c + 1], s1);
  atomicAdd(&Q[c], q0); atomicAdd(&Q[c + 1], q1);
}

__global__ void bnparams_k(const float* __restrict__ S, const float* __restrict__ Q,
                           const float* __restrict__ g, const float* __restrict__ b,
                           float* __restrict__ sc, float* __restrict__ sh) {
  const int t = threadIdx.x;  // 512
  const float m = S[t] * (1.0f / 16384.0f);
  const float v = Q[t] * (1.0f / 16384.0f) - m * m;
  const float inv = rsqrtf(v + 1e-5f);
  const float s = g[t] * inv;
  sc[t] = s;
  sh[t] = b[t] - m * s;
}

// ---------- BN + ReLU + split to bf16 hi/lo (NHWC -> NHWC) ----------
__global__ __launch_bounds__(256) void bnact_k(const float* __restrict__ X,
                                               const float* __restrict__ sc,
                                               const float* __restrict__ sh,
                                               ushort_t* __restrict__ H,
                                               ushort_t* __restrict__ L) {
  const size_t i0 = ((size_t)blockIdx.x * 256 + threadIdx.x) * 16;
  const int c0 = (int)(i0 & 511);
#pragma unroll
  for (int q = 0; q < 4; ++q) {
    const f32x4 v = *(const f32x4*)&X[i0 + q * 4];
    const f32x4 s = *(const f32x4*)&sc[c0 + q * 4];
    const f32x4 d = *(const f32x4*)&sh[c0 + q * 4];
    u16x4 h, l;
#pragma unroll
    for (int j = 0; j < 4; ++j) {
      float y = fmaf(v[j], s[j], d[j]);
      y = fmaxf(y, 0.f);
      ushort_t hh = f2bf(y);
      h[j] = hh;
      l[j] = f2bf(y - bf2f(hh));
    }
    *(u16x4*)&H[i0 + q * 4] = h;
    *(u16x4*)&L[i0 + q * 4] = l;
  }
}

// ---------- BN + ReLU + NHWC->NCHW fp32 (first output) ----------
__global__ __launch_bounds__(256) void bn_nchw_k(const float* __restrict__ X,
                                                 const float* __restrict__ sc,
                                                 const float* __restrict__ sh,
                                                 float* __restrict__ O) {
  __shared__ float T[64][65];
  const int t = threadIdx.x;
  const int p0 = blockIdx.x * 64;
  const int c0 = blockIdx.y * 64;
  const int b = p0 >> 12, pin0 = p0 & 4095;
#pragma unroll
  for (int it = 0; it < 4; ++it) {
    const int pl = it * 16 + (t >> 4);
    const int cl = (t & 15) * 4;
    const f32x4 v = *(const f32x4*)&X[((size_t)(p0 + pl)) * 512 + c0 + cl];
#pragma unroll
    for (int j = 0; j < 4; ++j) {
      float y = fmaf(v[j], sc[c0 + cl + j], sh[c0 + cl + j]);
      T[pl][cl + j] = fmaxf(y, 0.f);
    }
  }
  __syncthreads();
#pragma unroll
  for (int it = 0; it < 4; ++it) {
    const int cl = it * 16 + (t >> 4);
    const int pl = (t & 15) * 4;
    f32x4 o;
#pragma unroll
    for (int j = 0; j < 4; ++j) o[j] = T[pl + j][cl];
    *(f32x4*)&O[((size_t)(b * 512 + c0 + cl)) * 4096 + pin0 + pl] = o;
  }
}

// ---------- 1x1 classifier: (BN+ReLU)(conv1_raw) x W4 + b4 -> NCHW ----------
__global__ __launch_bounds__(256) void conv4_k(const float* __restrict__ X,
                                               const float* __restrict__ sc,
                                               const float* __restrict__ sh,
                                               const float* __restrict__ W4,
                                               const float* __restrict__ B4,
                                               float* __restrict__ O) {
  __shared__ float A[256][69];
  __shared__ float WL[64][19];
  const int t = threadIdx.x;
  const int g0 = blockIdx.x * 256;
  float acc[19];
#pragma unroll
  for (int n = 0; n < 19; ++n) acc[n] = 0.f;
  for (int kc = 0; kc < 8; ++kc) {
    const int k0 = kc * 64;
    __syncthreads();
#pragma unroll
    for (int it = 0; it < 16; ++it) {
      const int rl = it * 16 + (t >> 4);
      const int cl = (t & 15) * 4;
      const f32x4 v = *(const f32x4*)&X[((size_t)(g0 + rl)) * 512 + k0 + cl];
#pragma unroll
      for (int j = 0; j < 4; ++j)
        A[rl][cl + j] = fmaxf(fmaf(v[j], sc[k0 + cl + j], sh[k0 + cl + j]), 0.f);
    }
    for (int e = t; e < 1216; e += 256) {
      int k = e / 19, n = e - k * 19;
      WL[k][n] = W4[(size_t)n * 512 + k0 + k];
    }
    __syncthreads();
#pragma unroll 8
    for (int k = 0; k < 64; ++k) {
      const float a = A[t][k];
#pragma unroll
      for (int n = 0; n < 19; ++n) acc[n] = fmaf(a, WL[k][n], acc[n]);
    }
  }
  const int g = g0 + t;
  const int b = g >> 12, pin = g & 4095;
#pragma unroll
  for (int n = 0; n < 19; ++n)
    O[((size_t)(b * 19 + n)) * 4096 + pin] = acc[n] + B4[n];
}

// ---------- main implicit-GEMM conv (split-bf16, 3 MFMA products) ----------
// BM=256, BN=128, BK=32. 512 threads = 8 waves (4Mx2N), wave tile 64x64.
// 3 LDS buffers x 48KB, counted vmcnt(6), 2-tile-deep prefetch, raw s_barrier.
// Slots (1KB each, lane l owns bytes [16l,16l+16)): [0..15] A_hi m-frags,
// [16..31] A_lo, [32..39] B_hi n-frags, [40..47] B_lo. Wave w stages slots 6w..6w+5.
template <int EPI>  // 0: fp32 NHWC store; 1: +bias then bf16 hi/lo NHWC store
__global__ __launch_bounds__(512, 1) void gemm_k(
    const ushort_t* __restrict__ A1h, const ushort_t* __restrict__ A1l, int C1,
    const ushort_t* __restrict__ A2h, const ushort_t* __restrict__ A2l, int C2,
    const ushort_t* __restrict__ Bh_, const ushort_t* __restrict__ Bl_,
    int taps, int Nc, int KS, const ushort_t* __restrict__ zp,
    float* __restrict__ Co, ushort_t* __restrict__ Ch, ushort_t* __restrict__ Cl,
    const float* __restrict__ bias) {
  __shared__ ushort_t lds[3][24576];  // 3 x 48KB = 144KB
  const int t = threadIdx.x;
  const int lane = t & 63;
  const int wid = t >> 6;            // 0..7
  const int wr = wid >> 1;           // 0..3 (M)
  const int wc = wid & 1;            // 0..1 (N)
  // XCD-clustered swizzle: xcd = gid%8 gets by in [8*xcd, 8*xcd+8), all bx.
  const int gid = blockIdx.x;
  const int xcd = gid & 7;
  const int k_ = gid >> 3;           // 0..31
  const int by = (xcd * 4 + (k_ >> 3)) * 2 + ((k_ & 7) >> 2);  // 0..63
  const int bx = k_ & 3;             // 0..3
  const int Ctot = C1 + C2;
  const int klo = (lane >> 4) * 8;

  // per-slot pixel coords (A slots only)
  int sph[6], spw[6], sb[6];
  ulong_t g6[6];
  int tap = 0, c0 = 0;
#pragma unroll
  for (int i = 0; i < 6; ++i) {
    const int s = wid * 6 + i;
    if (s < 32) {
      const int f = s & 15;
      const int row = by * 256 + f * 16 + (lane & 15);
      sb[i] = (row >> 12) * 4096;
      const int pin = row & 4095;
      sph[i] = pin >> 6;
      spw[i] = pin & 63;
    } else {
      sb[i] = sph[i] = spw[i] = 0;
    }
  }

  auto recompute = [&]() {
    const int kh = tap / 3;
    const int dy = (taps == 9) ? (kh - 1) : 0;
    const int dx = (taps == 9) ? (tap - kh * 3 - 1) : 0;
#pragma unroll
    for (int i = 0; i < 6; ++i) {
      const int s = wid * 6 + i;
      if (s < 32) {
        const bool lo = (s >= 16);
        const ushort_t* base;
        int C, cc;
        if (c0 < C1) { base = lo ? A1l : A1h; C = C1; cc = c0; }
        else         { base = lo ? A2l : A2h; C = C2; cc = c0 - C1; }
        const int h2 = sph[i] + dy, w2 = spw[i] + dx;
        const bool ok = ((unsigned)h2 < 64u) & ((unsigned)w2 < 64u);
        const int sp = sb[i] + (h2 << 6) + w2;
        const ushort_t* p = base + (size_t)sp * (size_t)C + cc + klo;
        g6[i] = ok ? (ulong_t)p : (ulong_t)zp;
      } else {
        const bool lo = (s >= 40);
        const int f = (s - 32) & 7;
        const ushort_t* base = lo ? Bl_ : Bh_;
        const int cout = bx * 128 + f * 16 + (lane & 15);
        g6[i] = (ulong_t)(base + ((size_t)(tap * Nc + cout)) * (size_t)Ctot + c0 + klo);
      }
    }
  };

  auto stage = [&](int buf) {
    ushort_t* lb = &lds[buf][wid * 6 * 512];
#pragma unroll
    for (int i = 0; i < 6; ++i) {
      gload16(g6[i], lb + i * 512);
      g6[i] += 64;  // +32 channels (bytes)
    }
  };

  auto advance = [&]() {
    c0 += 32;
    if (c0 == Ctot) {
      c0 = 0;
      ++tap;
      if (tap < taps) recompute();
    } else if (c0 == C1 && C2 > 0) {
      recompute();  // concat region switch
    }
  };

  f32x4 acc[4][4];
#pragma unroll
  for (int i = 0; i < 4; ++i)
#pragma unroll
    for (int j = 0; j < 4; ++j) acc[i][j] = (f32x4){0.f, 0.f, 0.f, 0.f};

  recompute();
  stage(0); advance();
  __builtin_amdgcn_sched_barrier(0);   // keep the two prologue stages ordered (vmcnt FIFO)
  stage(1); advance();
  __builtin_amdgcn_sched_barrier(0);

  const int lofs = lane * 8;
  for (int ks = 0; ks < KS; ++ks) {
    if (ks < KS - 1) asm volatile("s_waitcnt vmcnt(6)" ::: "memory");
    else             asm volatile("s_waitcnt vmcnt(0)" ::: "memory");
    __builtin_amdgcn_sched_barrier(0);
    __builtin_amdgcn_s_barrier();      // raw barrier: no compiler vmcnt(0) drain
    if (ks + 2 < KS) { stage((ks + 2) % 3); advance(); }
    const ushort_t* L = &lds[ks % 3][0];
    bf16x8 ah[4], al[4], bh[4], bl[4];
#pragma unroll
    for (int i = 0; i < 4; ++i) {
      ah[i] = *(const bf16x8*)(L + (wr * 4 + i) * 512 + lofs);
      al[i] = *(const bf16x8*)(L + (16 * 512) + (wr * 4 + i) * 512 + lofs);
      bh[i] = *(const bf16x8*)(L + (32 * 512) + (wc * 4 + i) * 512 + lofs);
      bl[i] = *(const bf16x8*)(L + (40 * 512) + (wc * 4 + i) * 512 + lofs);
    }
#pragma unroll
    for (int mi = 0; mi < 4; ++mi)
#pragma unroll
      for (int ni = 0; ni < 4; ++ni)
        acc[mi][ni] = __builtin_amdgcn_mfma_f32_16x16x32_bf16(ah[mi], bh[ni], acc[mi][ni], 0, 0, 0);
#pragma unroll
    for (int mi = 0; mi < 4; ++mi)
#pragma unroll
      for (int ni = 0; ni < 4; ++ni) {
        acc[mi][ni] = __builtin_amdgcn_mfma_f32_16x16x32_bf16(ah[mi], bl[ni], acc[mi][ni], 0, 0, 0);
        acc[mi][ni] = __builtin_amdgcn_mfma_f32_16x16x32_bf16(al[mi], bh[ni], acc[mi][ni], 0, 0, 0);
      }
  }

  // epilogue: C/D layout col=lane&15, row=(lane>>4)*4+j  [m89-verified]
  const int row0 = by * 256 + wr * 64;
  const int col0 = bx * 128 + wc * 64;
  if (EPI == 0) {
#pragma unroll
    for (int mi = 0; mi < 4; ++mi)
#pragma unroll
      for (int ni = 0; ni < 4; ++ni) {
        const int c = col0 + ni * 16 + (lane & 15);
#pragma unroll
        for (int j = 0; j < 4; ++j) {
          const int r = row0 + mi * 16 + (lane >> 4) * 4 + j;
          Co[(size_t)r * Nc + c] = acc[mi][ni][j];
        }
      }
  } else {
#pragma unroll
    for (int ni = 0; ni < 4; ++ni) {
      const int c = col0 + ni * 16 + (lane & 15);
      const float bv = bias[c];
#pragma unroll
      for (int mi = 0; mi < 4; ++mi)
#pragma unroll
        for (int j = 0; j < 4; ++j) {
          const int r = row0 + mi * 16 + (lane >> 4) * 4 + j;
          float v = acc[mi][ni][j] + bv;
          ushort_t h = f2bf(v);
          float lo = v - bf2f(h);
          Ch[(size_t)r * Nc + c] = h;
          Cl[(size_t)r * Nc + c] = f2bf(lo);
        }
    }
  }
}

// ---------- host ----------
extern "C" void kernel_launch(void* const* d_in, const int* in_sizes, int n_in,
                              void* d_out, int out_size, void* d_ws, size_t ws_size,
                              hipStream_t stream) {
  const float* x  = (const float*)d_in[0];
  const float* Wa = (const float*)d_in[1];
  const float* ga = (const float*)d_in[2];
  const float* ba = (const float*)d_in[3];
  const float* Wb = (const float*)d_in[4];
  const float* bb = (const float*)d_in[5];
  const float* W1 = (const float*)d_in[6];
  const float* g1 = (const float*)d_in[7];
  const float* b1 = (const float*)d_in[8];
  const float* W4 = (const float*)d_in[9];
  const float* b4 = (const float*)d_in[10];
  float* out0 = (float*)d_out;
  float* outF = out0 + (size_t)4 * 512 * 64 * 64;

  char* ws = (char*)d_ws;
  size_t off = 0;
  auto take = [&](size_t bytes) -> char* {
    char* p = ws + off;
    off += (bytes + 255) & ~(size_t)255;
    return p;
  };
  ushort_t* zp  = (ushort_t*)take(8192);
  float* sumA = (float*)take(2048);
  float* ssA  = (float*)take(2048);
  float* scA  = (float*)take(2048);
  float* shA  = (float*)take(2048);
  float* sum1 = (float*)take(2048);
  float* ss1  = (float*)take(2048);
  float* sc1  = (float*)take(2048);
  float* sh1  = (float*)take(2048);
  ushort_t* xh  = (ushort_t*)take((size_t)16384 * 2048 * 2);
  ushort_t* xl  = (ushort_t*)take((size_t)16384 * 2048 * 2);
  ushort_t* wah = (ushort_t*)take((size_t)9 * 512 * 2048 * 2);
  ushort_t* wal = (ushort_t*)take((size_t)9 * 512 * 2048 * 2);
  ushort_t* w1h = (ushort_t*)take((size_t)9 * 512 * 2560 * 2);
  ushort_t* w1l = (ushort_t*)take((size_t)9 * 512 * 2560 * 2);
  ushort_t* wbh = (ushort_t*)take((size_t)512 * 512 * 2);
  ushort_t* wbl = (ushort_t*)take((size_t)512 * 512 * 2);
  char* r1 = take((size_t)16384 * 512 * 4);  // conva_raw f32, later outB hi/lo
  char* r2 = take((size_t)16384 * 512 * 4);  // outA hi/lo, later conv1_raw f32
  if (ws_size < off) return;  // workspace too small: bail (diagnosable next round)

  float* convaRaw = (float*)r1;
  ushort_t* oBh = (ushort_t*)r1;
  ushort_t* oBl = (ushort_t*)(r1 + (size_t)16384 * 512 * 2);
  ushort_t* oAh = (ushort_t*)r2;
  ushort_t* oAl = (ushort_t*)(r2 + (size_t)16384 * 512 * 2);
  float* conv1Raw = (float*)r2;

  zero_k<<<dim3(24), dim3(256), 0, stream>>>((float*)ws, 6144);
  cvt_x_k<<<dim3(256, 32), dim3(256), 0, stream>>>(x, xh, xl);
  cvt_w3_k<<<dim3(8, 512), dim3(256), 0, stream>>>(Wa, wah, wal, 2048, 512);
  cvt_w3_k<<<dim3(10, 512), dim3(256), 0, stream>>>(W1, w1h, w1l, 2560, 512);
  cvt_e_k<<<dim3(1024), dim3(256), 0, stream>>>(Wb, wbh, wbl);

  // conva: 3x3, K = 9*2048, KS = 576
  gemm_k<0><<<dim3(256), dim3(512), 0, stream>>>(
      xh, xl, 2048, (const ushort_t*)nullptr, (const ushort_t*)nullptr, 0,
      wah, wal, 9, 512, 576, zp, convaRaw, nullptr, nullptr, nullptr);
  stats_k<<<dim3(512), dim3(256), 0, stream>>>(convaRaw, sumA, ssA);
  bnparams_k<<<dim3(1), dim3(512), 0, stream>>>(sumA, ssA, ga, ba, scA, shA);
  bnact_k<<<dim3(2048), dim3(256), 0, stream>>>(convaRaw, scA, shA, oAh, oAl);

  // convb: 1x1 + bias, K = 512, KS = 16 (outputs split to bf16 hi/lo for concat)
  gemm_k<1><<<dim3(256), dim3(512), 0, stream>>>(
      oAh, oAl, 512, (const ushort_t*)nullptr, (const ushort_t*)nullptr, 0,
      wbh, wbl, 1, 512, 16, zp, nullptr, oBh, oBl, bb);

  // conv1: 3x3 over concat [x(2048) | outB(512)], K = 9*2560, KS = 720
  gemm_k<0><<<dim3(256), dim3(512), 0, stream>>>(
      xh, xl, 2048, oBh, oBl, 512,
      w1h, w1l, 9, 512, 720, zp, conv1Raw, nullptr, nullptr, nullptr);
  stats_k<<<dim3(512), dim3(256), 0, stream>>>(conv1Raw, sum1, ss1);
  bnparams_k<<<dim3(1), dim3(512), 0, stream>>>(sum1, ss1, g1, b1, sc1, sh1);

  bn_nchw_k<<<dim3(256, 8), dim3(256), 0, stream>>>(conv1Raw, sc1, sh1, out0);
  conv4_k<<<dim3(64), dim3(256), 0, stream>>>(conv1Raw, sc1, sh1, W4, b4, outF);
}

// Round 4
// 2010.176 us; speedup vs baseline: 3.4373x; 2.8165x over previous
//
#include <hip/hip_runtime.h>

typedef unsigned short ushort_t;
typedef unsigned int uint_t;
typedef unsigned long long ulong_t;

typedef __bf16 bf16x8 __attribute__((ext_vector_type(8)));
typedef float f32x4 __attribute__((ext_vector_type(4)));
typedef unsigned short u16x4 __attribute__((ext_vector_type(4)));

#define DEV __device__ __forceinline__
#define SB() __builtin_amdgcn_sched_barrier(0)
#define WAITV(n) asm volatile("s_waitcnt vmcnt(" #n ")" ::: "memory")

// ---------- helpers ----------
DEV ushort_t f2bf(float x) {  // RNE f32 -> bf16 bits
  uint_t u = __float_as_uint(x);
  u += 0x7fffu + ((u >> 16) & 1u);
  return (ushort_t)(u >> 16);
}
DEV float bf2f(ushort_t h) { return __uint_as_float(((uint_t)h) << 16); }

DEV void gload16(ulong_t g, const ushort_t* l) {
  __builtin_amdgcn_global_load_lds(
      (__attribute__((address_space(1))) void*)g,
      (__attribute__((address_space(3))) void*)(ushort_t*)l,
      16, 0, 0);
}
DEV int nxt3(int x) { return x == 2 ? 0 : x + 1; }

// ---------- zero init (zero page + stats) ----------
__global__ void zero_k(float* __restrict__ p, int n) {
  int i = blockIdx.x * 256 + threadIdx.x;
  if (i < n) p[i] = 0.f;
}

// ---------- x: NCHW f32 -> packed [px][cb][2][32] bf16 hi/lo ----------
__global__ __launch_bounds__(256) void cvt_x_k(const float* __restrict__ X,
                                               ushort_t* __restrict__ P) {
  __shared__ float T[64][65];
  const int t = threadIdx.x;
  const int p0 = blockIdx.x * 64;  // pixel base (0..16383)
  const int c0 = blockIdx.y * 64;  // channel base
  const int b = p0 >> 12;
  const int pin0 = p0 & 4095;
#pragma unroll
  for (int it = 0; it < 4; ++it) {
    const int cl = it * 16 + (t >> 4);
    const int pl = (t & 15) * 4;
    const f32x4 v = *(const f32x4*)&X[((size_t)(b * 2048 + c0 + cl)) * 4096 + pin0 + pl];
#pragma unroll
    for (int j = 0; j < 4; ++j) T[cl][pl + j] = v[j];
  }
  __syncthreads();
#pragma unroll
  for (int it = 0; it < 4; ++it) {
    const int pl = it * 16 + (t >> 4);
    const int cl = (t & 15) * 4;
    u16x4 h, l;
#pragma unroll
    for (int j = 0; j < 4; ++j) {
      float v = T[cl + j][pl];
      ushort_t hh = f2bf(v);
      h[j] = hh;
      l[j] = f2bf(v - bf2f(hh));
    }
    const int c = c0 + cl;
    const size_t o = (size_t)(p0 + pl) * 4096 + (size_t)((c >> 5) << 6) + (c & 31);
    *(u16x4*)&P[o] = h;
    *(u16x4*)&P[o + 32] = l;
  }
}

// ---------- 3x3 weights: OIHW f32 -> [tap][O][cb][2][32] ----------
__global__ __launch_bounds__(256) void cvt_w3_k(const float* __restrict__ W,
                                                ushort_t* __restrict__ P,
                                                int I, int O) {
  const int t = threadIdx.x;
  const int o = blockIdx.y;
  const int i = blockIdx.x * 256 + t;
  const float* src = W + ((size_t)o * I + i) * 9;
  float v[9];
#pragma unroll
  for (int j = 0; j < 9; ++j) v[j] = src[j];
#pragma unroll
  for (int j = 0; j < 9; ++j) {
    ushort_t h = f2bf(v[j]);
    const size_t d = (size_t)(j * O + o) * (I * 2) + (size_t)((i >> 5) << 6) + (i & 31);
    P[d] = h;
    P[d + 32] = f2bf(v[j] - bf2f(h));
  }
}

// ---------- Wb (1x1): [O][I] f32 -> [O][cb][2][32] ----------
__global__ __launch_bounds__(256) void cvt_e_k(const float* __restrict__ W,
                                               ushort_t* __restrict__ P) {
  int i = blockIdx.x * 256 + threadIdx.x;  // flat over 512*512
  float v = W[i];
  ushort_t h = f2bf(v);
  const int o = i >> 9, ic = i & 511;
  const size_t d = (size_t)o * 1024 + (size_t)((ic >> 5) << 6) + (ic & 31);
  P[d] = h;
  P[d + 32] = f2bf(v - bf2f(h));
}

// ---------- per-channel sum / sumsq over [16384][512] f32 ----------
__global__ __launch_bounds__(256) void stats_k(const float* __restrict__ X,
                                               float* __restrict__ S,
                                               float* __restrict__ Q) {
  const int t = threadIdx.x;
  const int r0 = blockIdx.x * 32;
  const int c = t * 2;
  float s0 = 0, s1 = 0, q0 = 0, q1 = 0;
  for (int r = 0; r < 32; ++r) {
    const float2 v = *(const float2*)&X[((size_t)(r0 + r)) * 512 + c];
    s0 += v.x; s1 += v.y;
    q0 += v.x * v.x; q1 += v.y * v.y;
  }
  atomicAdd(&S[c], s0); atomicAdd(&S[c + 1], s1);
  atomicAdd(&Q[c], q0); atomicAdd(&Q[c + 1], q1);
}

__global__ void bnparams_k(const float* __restrict__ S, const float* __restrict__ Q,
                           const float* __restrict__ g, const float* __restrict__ b,
                           float* __restrict__ sc, float* __restrict__ sh) {
  const int t = threadIdx.x;  // 512
  const float m = S[t] * (1.0f / 16384.0f);
  const float v = Q[t] * (1.0f / 16384.0f) - m * m;
  const float inv = rsqrtf(v + 1e-5f);
  const float s = g[t] * inv;
  sc[t] = s;
  sh[t] = b[t] - m * s;
}

// ---------- BN + ReLU + split -> packed [px][cb][2][32] ----------
__global__ __launch_bounds__(256) void bnact_k(const float* __restrict__ X,
                                               const float* __restrict__ sc,
                                               const float* __restrict__ sh,
                                               ushort_t* __restrict__ P) {
  const size_t i0 = ((size_t)blockIdx.x * 256 + threadIdx.x) * 16;
  const int c0 = (int)(i0 & 511);
  const size_t px = i0 >> 9;
#pragma unroll
  for (int q = 0; q < 4; ++q) {
    const f32x4 v = *(const f32x4*)&X[i0 + q * 4];
    const f32x4 s = *(const f32x4*)&sc[c0 + q * 4];
    const f32x4 d = *(const f32x4*)&sh[c0 + q * 4];
    u16x4 h, l;
#pragma unroll
    for (int j = 0; j < 4; ++j) {
      float y = fmaf(v[j], s[j], d[j]);
      y = fmaxf(y, 0.f);
      ushort_t hh = f2bf(y);
      h[j] = hh;
      l[j] = f2bf(y - bf2f(hh));
    }
    const int c = c0 + q * 4;
    const size_t o = px * 1024 + (size_t)((c >> 5) << 6) + (c & 31);
    *(u16x4*)&P[o] = h;
    *(u16x4*)&P[o + 32] = l;
  }
}

// ---------- BN + ReLU + NHWC->NCHW fp32 (first output) ----------
__global__ __launch_bounds__(256) void bn_nchw_k(const float* __restrict__ X,
                                                 const float* __restrict__ sc,
                                                 const float* __restrict__ sh,
                                                 float* __restrict__ O) {
  __shared__ float T[64][65];
  const int t = threadIdx.x;
  const int p0 = blockIdx.x * 64;
  const int c0 = blockIdx.y * 64;
  const int b = p0 >> 12, pin0 = p0 & 4095;
#pragma unroll
  for (int it = 0; it < 4; ++it) {
    const int pl = it * 16 + (t >> 4);
    const int cl = (t & 15) * 4;
    const f32x4 v = *(const f32x4*)&X[((size_t)(p0 + pl)) * 512 + c0 + cl];
#pragma unroll
    for (int j = 0; j < 4; ++j) {
      float y = fmaf(v[j], sc[c0 + cl + j], sh[c0 + cl + j]);
      T[pl][cl + j] = fmaxf(y, 0.f);
    }
  }
  __syncthreads();
#pragma unroll
  for (int it = 0; it < 4; ++it) {
    const int cl = it * 16 + (t >> 4);
    const int pl = (t & 15) * 4;
    f32x4 o;
#pragma unroll
    for (int j = 0; j < 4; ++j) o[j] = T[pl + j][cl];
    *(f32x4*)&O[((size_t)(b * 512 + c0 + cl)) * 4096 + pin0 + pl] = o;
  }
}

// ---------- 1x1 classifier ----------
__global__ __launch_bounds__(256) void conv4_k(const float* __restrict__ X,
                                               const float* __restrict__ sc,
                                               const float* __restrict__ sh,
                                               const float* __restrict__ W4,
                                               const float* __restrict__ B4,
                                               float* __restrict__ O) {
  __shared__ float A[256][69];
  __shared__ float WL[64][19];
  const int t = threadIdx.x;
  const int g0 = blockIdx.x * 256;
  float acc[19];
#pragma unroll
  for (int n = 0; n < 19; ++n) acc[n] = 0.f;
  for (int kc = 0; kc < 8; ++kc) {
    const int k0 = kc * 64;
    __syncthreads();
#pragma unroll
    for (int it = 0; it < 16; ++it) {
      const int rl = it * 16 + (t >> 4);
      const int cl = (t & 15) * 4;
      const f32x4 v = *(const f32x4*)&X[((size_t)(g0 + rl)) * 512 + k0 + cl];
#pragma unroll
      for (int j = 0; j < 4; ++j)
        A[rl][cl + j] = fmaxf(fmaf(v[j], sc[k0 + cl + j], sh[k0 + cl + j]), 0.f);
    }
    for (int e = t; e < 1216; e += 256) {
      int k = e / 19, n = e - k * 19;
      WL[k][n] = W4[(size_t)n * 512 + k0 + k];
    }
    __syncthreads();
#pragma unroll 8
    for (int k = 0; k < 64; ++k) {
      const float a = A[t][k];
#pragma unroll
      for (int n = 0; n < 19; ++n) acc[n] = fmaf(a, WL[k][n], acc[n]);
    }
  }
  const int g = g0 + t;
  const int b = g >> 12, pin = g & 4095;
#pragma unroll
  for (int n = 0; n < 19; ++n)
    O[((size_t)(b * 19 + n)) * 4096 + pin] = acc[n] + B4[n];
}

// ---------- main conv: tap-reuse implicit GEMM, split-bf16 ----------
// BM=256 (4 image rows), BN=128, BK=32 ch. 512 thr = 8 waves (4M x 2N).
// A window: (4+halo) rows x 64 w x 32 ch x {hi,lo}, [px][ch] layout with
// rotate-granule swizzle; staged via gload16 with inverse-rotated source.
// B: frag-blocked 1KB slots [16 cout][32 ch] x 8nf x 2dt = 16KB per tap-step,
// 3-buffer ring, staged 2 tap-steps ahead. Counted vmcnt, raw s_barrier.
template <int TAPS, int EPI>
__global__ __launch_bounds__(512, 1) void conv_k(
    const ushort_t* __restrict__ A1, int S1, int CB1,
    const ushort_t* __restrict__ A2, int S2, int CB2,
    const ushort_t* __restrict__ WB, int CBt,
    const ushort_t* __restrict__ zp,
    float* __restrict__ Co, ushort_t* __restrict__ Cp,
    const float* __restrict__ bias) {
  constexpr int RW = (TAPS == 9) ? 6 : 4;   // window rows
  constexpr int AJ = RW * 4;                // 16-px blocks per dtype
  constexpr int AI = (2 * AJ) / 8;          // A stage instr per wave (6/4)
  constexpr int APL = AJ * 1024;            // dtype plane bytes
  constexpr int ABUF = 2 * APL;             // A buffer bytes (48K/32K)
  constexpr int HO = (TAPS == 9) ? 64 : 0;  // halo row offset
  __shared__ ushort_t Alds[49152];  // 96KB: 2x48K (taps9) or 3x32K (taps1)
  __shared__ ushort_t Blds[24576];  // 48KB: 3x16K
  const int t = threadIdx.x, lane = t & 63, wid = t >> 6;
  const int wr = wid >> 1, wc = wid & 1;
  const int gid = blockIdx.x, xcd = gid & 7, k_ = gid >> 3;
  const int by = xcd * 8 + (k_ & 7), bx = k_ >> 3;
  const int b = by >> 4, r0 = (by & 15) * 4, bbase = b * 4096;
  const int gsrcA = ((lane & 3) - ((lane >> 3) & 3)) & 3;
  const int NBS = CBt * 64;  // cout stride (elements)

  auto stageA = [&](int cb, int bufA) {
#pragma unroll
    for (int i = 0; i < AI; ++i) {
      const int idx = wid * AI + i;
      const int d = idx / AJ, j = idx - d * AJ;
      const int irow = r0 + (j >> 2) - ((TAPS == 9) ? 1 : 0);
      int cbl = cb;
      const ushort_t* base = A1;
      int S = S1;
      if (CB2 > 0 && cbl >= CB1) { base = A2; S = S2; cbl -= CB1; }
      const int gpx = bbase + irow * 64 + (j & 3) * 16 + (lane >> 2);
      const ulong_t el = (ulong_t)gpx * (uint_t)S + (uint_t)(cbl * 64 + d * 32 + gsrcA * 8);
      const bool oob = (unsigned)irow >= 64u;
      const ulong_t src = oob ? (ulong_t)(zp + lane * 8) : (ulong_t)(base + el);
      gload16(src, (const ushort_t*)((const char*)Alds + bufA + (d * AJ + j) * 1024));
    }
  };
  auto stageB = [&](int cb, int tapIdx, int bufB) {
#pragma unroll
    for (int q = 0; q < 2; ++q) {
      const int s = wid * 2 + q, d = s >> 3, nf = s & 7;
      const int cout = bx * 128 + nf * 16 + (lane & 15);
      const ulong_t el = (ulong_t)(tapIdx * 512 + cout) * (uint_t)NBS +
                         (uint_t)(cb * 64 + d * 32 + (lane >> 4) * 8);
      gload16((ulong_t)(WB + el), (const ushort_t*)((const char*)Blds + bufB + s * 1024));
    }
  };

  f32x4 acc[4][4];
#pragma unroll
  for (int i = 0; i < 4; ++i)
#pragma unroll
    for (int j2 = 0; j2 < 4; ++j2) acc[i][j2] = (f32x4){0.f, 0.f, 0.f, 0.f};

  auto compute = [&](int abufB, int bbufB, int ro, int dx) {
    const char* Ab = (const char*)Alds + abufB;
    const char* Bb = (const char*)Blds + bbufB;
    bf16x8 ah[4], al[4], bh[4], bl[4];
#pragma unroll
    for (int i = 0; i < 4; ++i) {
      int px = wr * 64 + i * 16 + (lane & 15) + ro;
      px = px < 0 ? 0 : (px > RW * 64 - 1 ? RW * 64 - 1 : px);  // masked lanes only
      const int ao = px * 64 + ((((lane >> 4) + (px >> 1)) & 3) * 16);
      ah[i] = *(const bf16x8*)(Ab + ao);
      al[i] = *(const bf16x8*)(Ab + APL + ao);
      bh[i] = *(const bf16x8*)(Bb + (wc * 4 + i) * 1024 + lane * 16);
      bl[i] = *(const bf16x8*)(Bb + 8192 + (wc * 4 + i) * 1024 + lane * 16);
    }
    if (TAPS == 9) {  // horizontal pad masking (w edges)
      if (dx == -1 && (lane & 15) == 0) { bf16x8 z = {}; ah[0] = z; al[0] = z; }
      if (dx == 1 && (lane & 15) == 15) { bf16x8 z = {}; ah[3] = z; al[3] = z; }
    }
    __builtin_amdgcn_s_setprio(1);
#pragma unroll
    for (int mi = 0; mi < 4; ++mi)
#pragma unroll
      for (int ni = 0; ni < 4; ++ni)
        acc[mi][ni] = __builtin_amdgcn_mfma_f32_16x16x32_bf16(ah[mi], bh[ni], acc[mi][ni], 0, 0, 0);
#pragma unroll
    for (int mi = 0; mi < 4; ++mi)
#pragma unroll
      for (int ni = 0; ni < 4; ++ni) {
        acc[mi][ni] = __builtin_amdgcn_mfma_f32_16x16x32_bf16(ah[mi], bl[ni], acc[mi][ni], 0, 0, 0);
        acc[mi][ni] = __builtin_amdgcn_mfma_f32_16x16x32_bf16(al[mi], bh[ni], acc[mi][ni], 0, 0, 0);
      }
    __builtin_amdgcn_s_setprio(0);
  };

  if constexpr (TAPS == 9) {
    int bT = 0;
    stageA(0, 0); SB();
    stageB(0, 0, 0); SB();
    stageB(0, 1, 16384); SB();
    for (int cs = 0; cs < CBt; ++cs) {
      const int abufB = (cs & 1) * ABUF;
#pragma unroll
      for (int tap = 0; tap < 9; ++tap) {
        const int dy = tap / 3 - 1, dx = tap % 3 - 1;
        SB();
        if (tap == 8) { WAITV(8); } else { WAITV(2); }
        SB();
        __builtin_amdgcn_s_barrier();
        SB();
        const int tgt = nxt3(nxt3(bT)) * 16384;
        if (tap < 7) {
          stageB(cs, tap + 2, tgt);
        } else if (tap == 7) {
          stageA(cs + 1, ((cs + 1) & 1) * ABUF);
          stageB(cs + 1, 0, tgt);
        } else {
          stageB(cs + 1, 1, tgt);
        }
        SB();
        compute(abufB, bT * 16384, HO + dy * 64 + dx, dx);
        bT = nxt3(bT);
      }
    }
  } else {
    int rr = 0;
    stageA(0, 0); SB();
    stageB(0, 0, 0); SB();
    stageA(1, ABUF); SB();
    stageB(1, 0, 16384); SB();
    for (int cs = 0; cs < CBt; ++cs) {
      SB();
      WAITV(6);
      SB();
      __builtin_amdgcn_s_barrier();
      SB();
      const int rr2 = nxt3(nxt3(rr));
      stageA(cs + 2, rr2 * ABUF);
      stageB(cs + 2, 0, rr2 * 16384);
      SB();
      compute(rr * ABUF, rr * 16384, 0, 0);
      rr = nxt3(rr);
    }
  }

  // epilogue: C/D layout col=lane&15, row=(lane>>4)*4+j
  const int row0 = by * 256 + wr * 64;
  const int col0 = bx * 128 + wc * 64;
  if (EPI == 0) {
#pragma unroll
    for (int mi = 0; mi < 4; ++mi)
#pragma unroll
      for (int ni = 0; ni < 4; ++ni) {
        const int c = col0 + ni * 16 + (lane & 15);
#pragma unroll
        for (int j2 = 0; j2 < 4; ++j2) {
          const int r = row0 + mi * 16 + (lane >> 4) * 4 + j2;
          Co[(size_t)r * 512 + c] = acc[mi][ni][j2];
        }
      }
  } else {
#pragma unroll
    for (int ni = 0; ni < 4; ++ni) {
      const int c = col0 + ni * 16 + (lane & 15);
      const float bv = bias[c];
      const size_t cg = (size_t)((c >> 5) << 6) + (c & 31);
#pragma unroll
      for (int mi = 0; mi < 4; ++mi)
#pragma unroll
        for (int j2 = 0; j2 < 4; ++j2) {
          const int r = row0 + mi * 16 + (lane >> 4) * 4 + j2;
          const float v = acc[mi][ni][j2] + bv;
          const ushort_t h = f2bf(v);
          Cp[(size_t)r * 1024 + cg] = h;
          Cp[(size_t)r * 1024 + cg + 32] = f2bf(v - bf2f(h));
        }
    }
  }
}

// ---------- host ----------
extern "C" void kernel_launch(void* const* d_in, const int* in_sizes, int n_in,
                              void* d_out, int out_size, void* d_ws, size_t ws_size,
                              hipStream_t stream) {
  const float* x  = (const float*)d_in[0];
  const float* Wa = (const float*)d_in[1];
  const float* ga = (const float*)d_in[2];
  const float* ba = (const float*)d_in[3];
  const float* Wb = (const float*)d_in[4];
  const float* bb = (const float*)d_in[5];
  const float* W1 = (const float*)d_in[6];
  const float* g1 = (const float*)d_in[7];
  const float* b1 = (const float*)d_in[8];
  const float* W4 = (const float*)d_in[9];
  const float* b4 = (const float*)d_in[10];
  float* out0 = (float*)d_out;
  float* outF = out0 + (size_t)4 * 512 * 64 * 64;

  char* ws = (char*)d_ws;
  size_t off = 0;
  auto take = [&](size_t bytes) -> char* {
    char* p = ws + off;
    off += (bytes + 255) & ~(size_t)255;
    return p;
  };
  const size_t PAD = 16384;  // tail-prefetch overrun pad (bytes)
  ushort_t* zp  = (ushort_t*)take(8192);
  float* sumA = (float*)take(2048);
  float* ssA  = (float*)take(2048);
  float* scA  = (float*)take(2048);
  float* shA  = (float*)take(2048);
  float* sum1 = (float*)take(2048);
  float* ss1  = (float*)take(2048);
  float* sc1  = (float*)take(2048);
  float* sh1  = (float*)take(2048);
  ushort_t* X2  = (ushort_t*)take((size_t)16384 * 4096 * 2 + PAD);
  ushort_t* WA2 = (ushort_t*)take((size_t)9 * 512 * 4096 * 2 + PAD);
  ushort_t* W12 = (ushort_t*)take((size_t)9 * 512 * 5120 * 2 + PAD);
  ushort_t* WBb = (ushort_t*)take((size_t)512 * 1024 * 2 + PAD);
  ushort_t* oA2 = (ushort_t*)take((size_t)16384 * 1024 * 2 + PAD);
  ushort_t* oB2 = (ushort_t*)take((size_t)16384 * 1024 * 2 + PAD);
  float* convaRaw = (float*)take((size_t)16384 * 512 * 4);
  float* conv1Raw = (float*)take((size_t)16384 * 512 * 4);
  if (ws_size < off) return;

  zero_k<<<dim3(24), dim3(256), 0, stream>>>((float*)ws, 6144);
  cvt_x_k<<<dim3(256, 32), dim3(256), 0, stream>>>(x, X2);
  cvt_w3_k<<<dim3(8, 512), dim3(256), 0, stream>>>(Wa, WA2, 2048, 512);
  cvt_w3_k<<<dim3(10, 512), dim3(256), 0, stream>>>(W1, W12, 2560, 512);
  cvt_e_k<<<dim3(1024), dim3(256), 0, stream>>>(Wb, WBb);

  // conva: 3x3, Ctot=2048 (CBt=64)
  conv_k<9, 0><<<dim3(256), dim3(512), 0, stream>>>(
      X2, 4096, 66, X2, 4096, 0, WA2, 64, zp, convaRaw, nullptr, nullptr);
  stats_k<<<dim3(512), dim3(256), 0, stream>>>(convaRaw, sumA, ssA);
  bnparams_k<<<dim3(1), dim3(512), 0, stream>>>(sumA, ssA, ga, ba, scA, shA);
  bnact_k<<<dim3(2048), dim3(256), 0, stream>>>(convaRaw, scA, shA, oA2);

  // convb: 1x1 + bias, Ctot=512 (CBt=16), packed bf16 hi/lo out
  conv_k<1, 1><<<dim3(256), dim3(512), 0, stream>>>(
      oA2, 1024, 18, oA2, 1024, 0, WBb, 16, zp, nullptr, oB2, bb);

  // conv1: 3x3 over concat [x(64cb) | oB(16cb)], CBt=80
  conv_k<9, 0><<<dim3(256), dim3(512), 0, stream>>>(
      X2, 4096, 64, oB2, 1024, 16, W12, 80, zp, conv1Raw, nullptr, nullptr);
  stats_k<<<dim3(512), dim3(256), 0, stream>>>(conv1Raw, sum1, ss1);
  bnparams_k<<<dim3(1), dim3(512), 0, stream>>>(sum1, ss1, g1, b1, sc1, sh1);

  bn_nchw_k<<<dim3(256, 8), dim3(256), 0, stream>>>(conv1Raw, sc1, sh1, out0);
  conv4_k<<<dim3(64), dim3(256), 0, stream>>>(conv1Raw, sc1, sh1, W4, b4, outF);
}

// Round 8
// 1979.254 us; speedup vs baseline: 3.4910x; 1.0156x over previous
//
#include <hip/hip_runtime.h>

typedef unsigned short ushort_t;
typedef unsigned int uint_t;
typedef unsigned long long ulong_t;

typedef __bf16 bf16x8 __attribute__((ext_vector_type(8)));
typedef float f32x4 __attribute__((ext_vector_type(4)));
typedef float f32x16 __attribute__((ext_vector_type(16)));
typedef unsigned short u16x4 __attribute__((ext_vector_type(4)));

#define DEV __device__ __forceinline__
#define SB() __builtin_amdgcn_sched_barrier(0)
#define WAITV(n) asm volatile("s_waitcnt vmcnt(" #n ")" ::: "memory")

// ---------- helpers ----------
DEV ushort_t f2bf(float x) {  // RNE f32 -> bf16 bits
  uint_t u = __float_as_uint(x);
  u += 0x7fffu + ((u >> 16) & 1u);
  return (ushort_t)(u >> 16);
}
DEV float bf2f(ushort_t h) { return __uint_as_float(((uint_t)h) << 16); }

DEV void gload16(ulong_t g, const void* l) {
  __builtin_amdgcn_global_load_lds(
      (__attribute__((address_space(1))) void*)g,
      (__attribute__((address_space(3))) void*)(void*)l,
      16, 0, 0);
}
DEV int nxt3(int x) { return x == 2 ? 0 : x + 1; }

// ---------- zero init (zero page + stats) ----------
__global__ void zero_k(float* __restrict__ p, int n) {
  int i = blockIdx.x * 256 + threadIdx.x;
  if (i < n) p[i] = 0.f;
}

// ---------- x: NCHW f32 -> packed [px][cb][2][32] bf16 hi/lo ----------
__global__ __launch_bounds__(256) void cvt_x_k(const float* __restrict__ X,
                                               ushort_t* __restrict__ P) {
  __shared__ float T[64][65];
  const int t = threadIdx.x;
  const int p0 = blockIdx.x * 64;  // pixel base (0..16383)
  const int c0 = blockIdx.y * 64;  // channel base
  const int b = p0 >> 12;
  const int pin0 = p0 & 4095;
#pragma unroll
  for (int it = 0; it < 4; ++it) {
    const int cl = it * 16 + (t >> 4);
    const int pl = (t & 15) * 4;
    const f32x4 v = *(const f32x4*)&X[((size_t)(b * 2048 + c0 + cl)) * 4096 + pin0 + pl];
#pragma unroll
    for (int j = 0; j < 4; ++j) T[cl][pl + j] = v[j];
  }
  __syncthreads();
#pragma unroll
  for (int it = 0; it < 4; ++it) {
    const int pl = it * 16 + (t >> 4);
    const int cl = (t & 15) * 4;
    u16x4 h, l;
#pragma unroll
    for (int j = 0; j < 4; ++j) {
      float v = T[cl + j][pl];
      ushort_t hh = f2bf(v);
      h[j] = hh;
      l[j] = f2bf(v - bf2f(hh));
    }
    const int c = c0 + cl;
    const size_t o = (size_t)(p0 + pl) * 4096 + (size_t)((c >> 5) << 6) + (c & 31);
    *(u16x4*)&P[o] = h;
    *(u16x4*)&P[o + 32] = l;
  }
}

// ---------- 3x3 weights: OIHW f32 -> [tap][O][cb][2][32] ----------
__global__ __launch_bounds__(256) void cvt_w3_k(const float* __restrict__ W,
                                                ushort_t* __restrict__ P,
                                                int I, int O) {
  const int t = threadIdx.x;
  const int o = blockIdx.y;
  const int i = blockIdx.x * 256 + t;
  const float* src = W + ((size_t)o * I + i) * 9;
  float v[9];
#pragma unroll
  for (int j = 0; j < 9; ++j) v[j] = src[j];
#pragma unroll
  for (int j = 0; j < 9; ++j) {
    ushort_t h = f2bf(v[j]);
    const size_t d = (size_t)(j * O + o) * (I * 2) + (size_t)((i >> 5) << 6) + (i & 31);
    P[d] = h;
    P[d + 32] = f2bf(v[j] - bf2f(h));
  }
}

// ---------- Wb (1x1): [O][I] f32 -> [O][cb][2][32] ----------
__global__ __launch_bounds__(256) void cvt_e_k(const float* __restrict__ W,
                                               ushort_t* __restrict__ P) {
  int i = blockIdx.x * 256 + threadIdx.x;  // flat over 512*512
  float v = W[i];
  ushort_t h = f2bf(v);
  const int o = i >> 9, ic = i & 511;
  const size_t d = (size_t)o * 1024 + (size_t)((ic >> 5) << 6) + (ic & 31);
  P[d] = h;
  P[d + 32] = f2bf(v - bf2f(h));
}

// ---------- per-channel sum / sumsq over [16384][512] f32 ----------
__global__ __launch_bounds__(256) void stats_k(const float* __restrict__ X,
                                               float* __restrict__ S,
                                               float* __restrict__ Q) {
  const int t = threadIdx.x;
  const int r0 = blockIdx.x * 32;
  const int c = t * 2;
  float s0 = 0, s1 = 0, q0 = 0, q1 = 0;
  for (int r = 0; r < 32; ++r) {
    const float2 v = *(const float2*)&X[((size_t)(r0 + r)) * 512 + c];
    s0 += v.x; s1 += v.y;
    q0 += v.x * v.x; q1 += v.y * v.y;
  }
  atomicAdd(&S[c], s0); atomicAdd(&S[c + 1], s1);
  atomicAdd(&Q[c], q0); atomicAdd(&Q[c + 1], q1);
}

__global__ void bnparams_k(const float* __restrict__ S, const float* __restrict__ Q,
                           const float* __restrict__ g, const float* __restrict__ b,
                           float* __restrict__ sc, float* __restrict__ sh) {
  const int t = threadIdx.x;  // 512
  const float m = S[t] * (1.0f / 16384.0f);
  const float v = Q[t] * (1.0f / 16384.0f) - m * m;
  const float inv = rsqrtf(v + 1e-5f);
  const float s = g[t] * inv;
  sc[t] = s;
  sh[t] = b[t] - m * s;
}

// ---------- BN + ReLU + split -> packed [px][cb][2][32] ----------
__global__ __launch_bounds__(256) void bnact_k(const float* __restrict__ X,
                                               const float* __restrict__ sc,
                                               const float* __restrict__ sh,
                                               ushort_t* __restrict__ P) {
  const size_t i0 = ((size_t)blockIdx.x * 256 + threadIdx.x) * 16;
  const int c0 = (int)(i0 & 511);
  const size_t px = i0 >> 9;
#pragma unroll
  for (int q = 0; q < 4; ++q) {
    const f32x4 v = *(const f32x4*)&X[i0 + q * 4];
    const f32x4 s = *(const f32x4*)&sc[c0 + q * 4];
    const f32x4 d = *(const f32x4*)&sh[c0 + q * 4];
    u16x4 h, l;
#pragma unroll
    for (int j = 0; j < 4; ++j) {
      float y = fmaf(v[j], s[j], d[j]);
      y = fmaxf(y, 0.f);
      ushort_t hh = f2bf(y);
      h[j] = hh;
      l[j] = f2bf(y - bf2f(hh));
    }
    const int c = c0 + q * 4;
    const size_t o = px * 1024 + (size_t)((c >> 5) << 6) + (c & 31);
    *(u16x4*)&P[o] = h;
    *(u16x4*)&P[o + 32] = l;
  }
}

// ---------- BN + ReLU + NHWC->NCHW fp32 (first output) ----------
__global__ __launch_bounds__(256) void bn_nchw_k(const float* __restrict__ X,
                                                 const float* __restrict__ sc,
                                                 const float* __restrict__ sh,
                                                 float* __restrict__ O) {
  __shared__ float T[64][65];
  const int t = threadIdx.x;
  const int p0 = blockIdx.x * 64;
  const int c0 = blockIdx.y * 64;
  const int b = p0 >> 12, pin0 = p0 & 4095;
#pragma unroll
  for (int it = 0; it < 4; ++it) {
    const int pl = it * 16 + (t >> 4);
    const int cl = (t & 15) * 4;
    const f32x4 v = *(const f32x4*)&X[((size_t)(p0 + pl)) * 512 + c0 + cl];
#pragma unroll
    for (int j = 0; j < 4; ++j) {
      float y = fmaf(v[j], sc[c0 + cl + j], sh[c0 + cl + j]);
      T[pl][cl + j] = fmaxf(y, 0.f);
    }
  }
  __syncthreads();
#pragma unroll
  for (int it = 0; it < 4; ++it) {
    const int cl = it * 16 + (t >> 4);
    const int pl = (t & 15) * 4;
    f32x4 o;
#pragma unroll
    for (int j = 0; j < 4; ++j) o[j] = T[pl + j][cl];
    *(f32x4*)&O[((size_t)(b * 512 + c0 + cl)) * 4096 + pin0 + pl] = o;
  }
}

// ---------- 1x1 classifier ----------
__global__ __launch_bounds__(256) void conv4_k(const float* __restrict__ X,
                                               const float* __restrict__ sc,
                                               const float* __restrict__ sh,
                                               const float* __restrict__ W4,
                                               const float* __restrict__ B4,
                                               float* __restrict__ O) {
  __shared__ float A[256][69];
  __shared__ float WL[64][19];
  const int t = threadIdx.x;
  const int g0 = blockIdx.x * 256;
  float acc[19];
#pragma unroll
  for (int n = 0; n < 19; ++n) acc[n] = 0.f;
  for (int kc = 0; kc < 8; ++kc) {
    const int k0 = kc * 64;
    __syncthreads();
#pragma unroll
    for (int it = 0; it < 16; ++it) {
      const int rl = it * 16 + (t >> 4);
      const int cl = (t & 15) * 4;
      const f32x4 v = *(const f32x4*)&X[((size_t)(g0 + rl)) * 512 + k0 + cl];
#pragma unroll
      for (int j = 0; j < 4; ++j)
        A[rl][cl + j] = fmaxf(fmaf(v[j], sc[k0 + cl + j], sh[k0 + cl + j]), 0.f);
    }
    for (int e = t; e < 1216; e += 256) {
      int k = e / 19, n = e - k * 19;
      WL[k][n] = W4[(size_t)n * 512 + k0 + k];
    }
    __syncthreads();
#pragma unroll 8
    for (int k = 0; k < 64; ++k) {
      const float a = A[t][k];
#pragma unroll
      for (int n = 0; n < 19; ++n) acc[n] = fmaf(a, WL[k][n], acc[n]);
    }
  }
  const int g = g0 + t;
  const int b = g >> 12, pin = g & 4095;
#pragma unroll
  for (int n = 0; n < 19; ++n)
    O[((size_t)(b * 19 + n)) * 4096 + pin] = acc[n] + B4[n];
}

// ---------- main conv: tap-reuse implicit GEMM, split-bf16, 32x32x16 MFMA ----------
// BM=256 (4 image rows), BN=128, BK=32 ch. 512 thr = 8 waves (4M x 2N),
// wave tile 64x64 = 2x2 frags of 32x32. Pair-tap phases: one vmcnt(0)+barrier
// per 2 taps; B ring of 4 x 16KB staged 2 taps ahead; A double-buffered 2x48KB.
// A operand: row=lane&31, k=(lane>>5)*8+e. C/D: col=lane&31,
// row=(reg&3)+8*(reg>>2)+4*(lane>>5)  [m74/m101].
template <int TAPS, int EPI>
__global__ __launch_bounds__(512, 2) void conv_k(
    const ushort_t* __restrict__ A1, int S1, int CB1,
    const ushort_t* __restrict__ A2, int S2, int CB2,
    const ushort_t* __restrict__ WB, int CBt,
    const ushort_t* __restrict__ zp,
    float* __restrict__ Co, ushort_t* __restrict__ Cp,
    const float* __restrict__ bias) {
  constexpr int RW = (TAPS == 9) ? 6 : 4;   // window rows
  constexpr int AJ = RW * 4;                // 16-px slots per dtype plane
  constexpr int AI = (2 * AJ) / 8;          // A stage instrs per wave (6/4)
  constexpr int APL = AJ * 1024;            // dtype plane bytes
  constexpr int ABUF = 2 * APL;             // A buffer bytes (48K/32K)
  constexpr int HO = (TAPS == 9) ? 64 : 0;  // halo px offset
  __shared__ char lds_all[163840];          // 96KB A region + 64KB B region
  char* Ald = lds_all;
  char* Bld = lds_all + 98304;
  const int t = threadIdx.x, lane = t & 63, wid = t >> 6;
  const int wr = wid >> 1, wc = wid & 1;
  const int gid = blockIdx.x, xcd = gid & 7, k_ = gid >> 3;
  const int by = xcd * 8 + (k_ & 7), bx = k_ >> 3;
  const int b = by >> 4, r0 = (by & 15) * 4, bbase = b * 4096;
  const int gsrc = ((lane & 3) - ((lane >> 3) & 3)) & 3;  // rotate-granule source
  const int NBS = CBt * 64;  // elements per cout per tap

  auto stageA = [&](int cb, int bufA) {
#pragma unroll
    for (int i = 0; i < AI; ++i) {
      const int idx = wid * AI + i;
      const int d = idx / AJ, j = idx - d * AJ;
      const int irow = r0 + (j >> 2) - ((TAPS == 9) ? 1 : 0);
      int cbl = cb;
      const ushort_t* base = A1;
      int S = S1;
      if (CB2 > 0 && cbl >= CB1) { base = A2; S = S2; cbl -= CB1; }
      const int gpx = bbase + irow * 64 + (j & 3) * 16 + (lane >> 2);
      const ulong_t el = (ulong_t)gpx * (uint_t)S + (uint_t)(cbl * 64 + d * 32 + gsrc * 8);
      const bool oob = (unsigned)irow >= 64u;
      const ulong_t src = oob ? (ulong_t)(zp + lane * 8) : (ulong_t)(base + el);
      gload16(src, Ald + bufA + (d * AJ + j) * 1024);
    }
  };
  auto stageB = [&](int cb, int tapIdx, int bufB) {
#pragma unroll
    for (int q = 0; q < 2; ++q) {
      const int s = wid * 2 + q;                 // 0..15
      const int d = s >> 3, r = s & 7, nb = r >> 1, h = r & 1;
      const int co = bx * 128 + nb * 32 + h * 16 + (lane >> 2);
      const ulong_t el = (ulong_t)(tapIdx * 512 + co) * (uint_t)NBS +
                         (uint_t)(cb * 64 + d * 32 + gsrc * 8);
      gload16((ulong_t)(WB + el), Bld + bufB + s * 1024);
    }
  };

  f32x16 acc[2][2];
#pragma unroll
  for (int i = 0; i < 2; ++i)
#pragma unroll
    for (int j2 = 0; j2 < 2; ++j2) acc[i][j2] = (f32x16){0.f};

  const int pxl = lane & 31;
  const int khalf = lane >> 5;     // 0/1 -> k += 8*khalf
  const int rotB = (pxl >> 1) & 3;
  // B read offsets are loop-invariant: precompute
  int boff[2][2];  // [ni][kk]
#pragma unroll
  for (int ni = 0; ni < 2; ++ni)
#pragma unroll
    for (int kk = 0; kk < 2; ++kk) {
      const int pos = (kk * 2 + khalf + rotB) & 3;
      boff[ni][kk] = (wc * 2 + ni) * 2048 + pxl * 64 + pos * 16;
    }

  auto compute = [&](int abufB, int bbufB, int ro, int dx) {
    const char* Ab = Ald + abufB;
    const char* Bb = Bld + bbufB;
    bf16x8 a[2][2][2], bf[2][2][2];  // [mi|ni][kk][dt]
#pragma unroll
    for (int mi = 0; mi < 2; ++mi)
#pragma unroll
      for (int kk = 0; kk < 2; ++kk) {
        int px = wr * 64 + mi * 32 + pxl + ro;
        px = px < 0 ? 0 : (px > RW * 64 - 1 ? RW * 64 - 1 : px);  // masked lanes only
        const int pos = (kk * 2 + khalf + (px >> 1)) & 3;
        const int ao = px * 64 + pos * 16;
        a[mi][kk][0] = *(const bf16x8*)(Ab + ao);
        a[mi][kk][1] = *(const bf16x8*)(Ab + APL + ao);
      }
#pragma unroll
    for (int ni = 0; ni < 2; ++ni)
#pragma unroll
      for (int kk = 0; kk < 2; ++kk) {
        bf[ni][kk][0] = *(const bf16x8*)(Bb + boff[ni][kk]);
        bf[ni][kk][1] = *(const bf16x8*)(Bb + 8192 + boff[ni][kk]);
      }
    if (TAPS == 9) {  // horizontal pad masking (w edges)
      if (dx == -1 && pxl == 0) {
        bf16x8 z = {};
        a[0][0][0] = z; a[0][0][1] = z; a[0][1][0] = z; a[0][1][1] = z;
      }
      if (dx == 1 && pxl == 31) {
        bf16x8 z = {};
        a[1][0][0] = z; a[1][0][1] = z; a[1][1][0] = z; a[1][1][1] = z;
      }
    }
    __builtin_amdgcn_s_setprio(1);
#pragma unroll
    for (int kk = 0; kk < 2; ++kk)
#pragma unroll
      for (int mi = 0; mi < 2; ++mi)
#pragma unroll
        for (int ni = 0; ni < 2; ++ni) {
          acc[mi][ni] = __builtin_amdgcn_mfma_f32_32x32x16_bf16(
              a[mi][kk][0], bf[ni][kk][0], acc[mi][ni], 0, 0, 0);
          acc[mi][ni] = __builtin_amdgcn_mfma_f32_32x32x16_bf16(
              a[mi][kk][0], bf[ni][kk][1], acc[mi][ni], 0, 0, 0);
          acc[mi][ni] = __builtin_amdgcn_mfma_f32_32x32x16_bf16(
              a[mi][kk][1], bf[ni][kk][0], acc[mi][ni], 0, 0, 0);
        }
    __builtin_amdgcn_s_setprio(0);
  };

  if constexpr (TAPS == 9) {
    const int NT = CBt * 9;
    stageA(0, 0);
    stageB(0, 0, 0);
    stageB(0, 1, 16384);
    SB();
    for (int T = 0; T < NT; T += 2) {
      WAITV(0);
      SB();
      __builtin_amdgcn_s_barrier();
      SB();
      const int T2 = T + 2, T3 = T + 3;
      if (T2 < NT) {
        const int cs2 = T2 / 9, tp2 = T2 - cs2 * 9;
        if (tp2 == 0) stageA(cs2, (cs2 & 1) * ABUF);
        stageB(cs2, tp2, (T2 & 3) * 16384);
      }
      if (T3 < NT) {
        const int cs3 = T3 / 9, tp3 = T3 - cs3 * 9;
        if (tp3 == 0) stageA(cs3, (cs3 & 1) * ABUF);
        stageB(cs3, tp3, (T3 & 3) * 16384);
      }
      SB();
      {
        const int cs = T / 9, tap = T - cs * 9;
        const int dy = tap / 3 - 1, dx = tap - (tap / 3) * 3 - 1;
        compute((cs & 1) * ABUF, (T & 3) * 16384, HO + dy * 64 + dx, dx);
      }
      {
        const int T1 = T + 1;
        const int cs = T1 / 9, tap = T1 - cs * 9;
        const int dy = tap / 3 - 1, dx = tap - (tap / 3) * 3 - 1;
        compute((cs & 1) * ABUF, (T1 & 3) * 16384, HO + dy * 64 + dx, dx);
      }
    }
  } else {
    int rr = 0;
    stageA(0, 0); SB();
    stageB(0, 0, 0); SB();
    stageA(1, ABUF); SB();
    stageB(1, 0, 16384); SB();
    for (int cs = 0; cs < CBt; ++cs) {
      SB();
      WAITV(6);
      SB();
      __builtin_amdgcn_s_barrier();
      SB();
      const int rr2 = nxt3(nxt3(rr));
      stageA(cs + 2, rr2 * ABUF);   // over-reads into PAD at tail (by design)
      stageB(cs + 2, 0, rr2 * 16384);
      SB();
      compute(rr * ABUF, rr * 16384, 0, 0);
      rr = nxt3(rr);
    }
  }

  // epilogue: C/D col=lane&31, row=(reg&3)+8*(reg>>2)+4*(lane>>5)
  const int row0 = by * 256 + wr * 64;
  const int col0 = bx * 128 + wc * 64;
  const int rb = 4 * khalf;
  if (EPI == 0) {
#pragma unroll
    for (int mi = 0; mi < 2; ++mi)
#pragma unroll
      for (int ni = 0; ni < 2; ++ni) {
        const int c = col0 + ni * 32 + pxl;
#pragma unroll
        for (int rg = 0; rg < 16; ++rg) {
          const int r = row0 + mi * 32 + (rg & 3) + 8 * (rg >> 2) + rb;
          Co[(size_t)r * 512 + c] = acc[mi][ni][rg];
        }
      }
  } else {
#pragma unroll
    for (int ni = 0; ni < 2; ++ni) {
      const int c = col0 + ni * 32 + pxl;
      const float bv = bias[c];
      const size_t cg = (size_t)((c >> 5) << 6) + (c & 31);
#pragma unroll
      for (int mi = 0; mi < 2; ++mi)
#pragma unroll
        for (int rg = 0; rg < 16; ++rg) {
          const int r = row0 + mi * 32 + (rg & 3) + 8 * (rg >> 2) + rb;
          const float v = acc[mi][ni][rg] + bv;
          const ushort_t h = f2bf(v);
          Cp[(size_t)r * 1024 + cg] = h;
          Cp[(size_t)r * 1024 + cg + 32] = f2bf(v - bf2f(h));
        }
    }
  }
}

// ---------- host ----------
extern "C" void kernel_launch(void* const* d_in, const int* in_sizes, int n_in,
                              void* d_out, int out_size, void* d_ws, size_t ws_size,
                              hipStream_t stream) {
  const float* x  = (const float*)d_in[0];
  const float* Wa = (const float*)d_in[1];
  const float* ga = (const float*)d_in[2];
  const float* ba = (const float*)d_in[3];
  const float* Wb = (const float*)d_in[4];
  const float* bb = (const float*)d_in[5];
  const float* W1 = (const float*)d_in[6];
  const float* g1 = (const float*)d_in[7];
  const float* b1 = (const float*)d_in[8];
  const float* W4 = (const float*)d_in[9];
  const float* b4 = (const float*)d_in[10];
  float* out0 = (float*)d_out;
  float* outF = out0 + (size_t)4 * 512 * 64 * 64;

  char* ws = (char*)d_ws;
  size_t off = 0;
  auto take = [&](size_t bytes) -> char* {
    char* p = ws + off;
    off += (bytes + 255) & ~(size_t)255;
    return p;
  };
  const size_t PAD = 16384;  // tail-prefetch overrun pad (bytes)
  ushort_t* zp  = (ushort_t*)take(8192);
  float* sumA = (float*)take(2048);
  float* ssA  = (float*)take(2048);
  float* scA  = (float*)take(2048);
  float* shA  = (float*)take(2048);
  float* sum1 = (float*)take(2048);
  float* ss1  = (float*)take(2048);
  float* sc1  = (float*)take(2048);
  float* sh1  = (float*)take(2048);
  ushort_t* X2  = (ushort_t*)take((size_t)16384 * 4096 * 2 + PAD);
  ushort_t* WA2 = (ushort_t*)take((size_t)9 * 512 * 4096 * 2 + PAD);
  ushort_t* W12 = (ushort_t*)take((size_t)9 * 512 * 5120 * 2 + PAD);
  ushort_t* WBb = (ushort_t*)take((size_t)512 * 1024 * 2 + PAD);
  ushort_t* oA2 = (ushort_t*)take((size_t)16384 * 1024 * 2 + PAD);
  ushort_t* oB2 = (ushort_t*)take((size_t)16384 * 1024 * 2 + PAD);
  float* convaRaw = (float*)take((size_t)16384 * 512 * 4);
  float* conv1Raw = (float*)take((size_t)16384 * 512 * 4);
  if (ws_size < off) return;

  zero_k<<<dim3(24), dim3(256), 0, stream>>>((float*)ws, 6144);
  cvt_x_k<<<dim3(256, 32), dim3(256), 0, stream>>>(x, X2);
  cvt_w3_k<<<dim3(8, 512), dim3(256), 0, stream>>>(Wa, WA2, 2048, 512);
  cvt_w3_k<<<dim3(10, 512), dim3(256), 0, stream>>>(W1, W12, 2560, 512);
  cvt_e_k<<<dim3(1024), dim3(256), 0, stream>>>(Wb, WBb);

  // conva: 3x3, Ctot=2048 (CBt=64)
  conv_k<9, 0><<<dim3(256), dim3(512), 0, stream>>>(
      X2, 4096, 64, X2, 4096, 0, WA2, 64, zp, convaRaw, nullptr, nullptr);
  stats_k<<<dim3(512), dim3(256), 0, stream>>>(convaRaw, sumA, ssA);
  bnparams_k<<<dim3(1), dim3(512), 0, stream>>>(sumA, ssA, ga, ba, scA, shA);
  bnact_k<<<dim3(2048), dim3(256), 0, stream>>>(convaRaw, scA, shA, oA2);

  // convb: 1x1 + bias, Ctot=512 (CBt=16), packed bf16 hi/lo out
  conv_k<1, 1><<<dim3(256), dim3(512), 0, stream>>>(
      oA2, 1024, 18, oA2, 1024, 0, WBb, 16, zp, nullptr, oB2, bb);

  // conv1: 3x3 over concat [x(64cb) | oB(16cb)], CBt=80
  conv_k<9, 0><<<dim3(256), dim3(512), 0, stream>>>(
      X2, 4096, 64, oB2, 1024, 16, W12, 80, zp, conv1Raw, nullptr, nullptr);
  stats_k<<<dim3(512), dim3(256), 0, stream>>>(conv1Raw, sum1, ss1);
  bnparams_k<<<dim3(1), dim3(512), 0, stream>>>(sum1, ss1, g1, b1, sc1, sh1);

  bn_nchw_k<<<dim3(256, 8), dim3(256), 0, stream>>>(conv1Raw, sc1, sh1, out0);
  conv4_k<<<dim3(64), dim3(256), 0, stream>>>(conv1Raw, sc1, sh1, W4, b4, outF);
}